// Round 7
// baseline (57.479 us; speedup 1.0000x reference)
//
#include <hip/hip_runtime.h>
#include <hip/hip_bf16.h>

#define B_ 2048
#define D_ 17
#define H_ 8
#define HID_ 256
#define OUT_ 23
#define XROW 8721       /* 513*17 floats per batch */
#define SEQN 8704       /* 512*17 seq floats per batch */

__device__ __forceinline__ float4 ld4u(const float* p) {   // 4B-aligned 16B load
  float4 v; __builtin_memcpy(&v, p, 16); return v;
}

// ---------------- Kernel 1: prep — transpose W2s + fold q into Wk ----------------
__global__ __launch_bounds__(256) void prep_kernel(
    const float* __restrict__ pW2, const float* __restrict__ vW2,
    const float* __restrict__ Wk, const float* __restrict__ bk,
    const float* __restrict__ q,
    float* __restrict__ pW2t, float* __restrict__ vW2t, float* __restrict__ qkc)
{
  const int bid = blockIdx.x;
  const int t = threadIdx.x;
  if (bid == 128) {
    if (t < H_ * D_) {
      const int h = t / D_, dd = t - h * D_;
      float s = 0.f;
      #pragma unroll
      for (int e = 0; e < D_; ++e) s = fmaf(Wk[h*289 + e*D_ + dd], q[h*D_ + e], s);
      qkc[h*18 + dd] = s;
    } else if (t < H_ * D_ + H_) {
      const int h = t - H_ * D_;
      float s = 0.f;
      #pragma unroll
      for (int e = 0; e < D_; ++e) s = fmaf(bk[h*D_ + e], q[h*D_ + e], s);
      qkc[h*18 + 17] = s;
    }
    return;
  }
  __shared__ float tile[32][33];
  const int m = bid >> 6, tid = bid & 63;
  const int ti = (tid >> 3) * 32, tk = (tid & 7) * 32;
  const float* src = m ? vW2 : pW2;
  float* dst = m ? vW2t : pW2t;
  const int tx = t & 31, ty = t >> 5;
  #pragma unroll
  for (int r = 0; r < 4; ++r) tile[ty + 8*r][tx] = src[(ti + ty + 8*r)*HID_ + tk + tx];
  __syncthreads();
  #pragma unroll
  for (int r = 0; r < 4; ++r) dst[(tk + ty + 8*r)*HID_ + ti + tx] = tile[tx][ty + 8*r];
}

// ---------------- Kernel 2: LDS-staged attention -> comb (B x 26) ----------------
// 1 batch/block, 256 thr = 4 waves. Probe length (64 strided word0 tests + ballot),
// bulk-stage live rows to LDS (9 independent float4 loads/thread -> high MLP, one
// barrier), then granule compute: lane=(head=l&7, rg=l>>3), 8 head-lanes broadcast-
// read the same granule (4 rows = 17 float4, conflict-free: bank stride 4*rg).
__global__ __launch_bounds__(256, 4) void attn_comb_kernel(
    const float* __restrict__ x, const float* __restrict__ qkc,
    const float* __restrict__ Wv, const float* __restrict__ bv,
    const float* __restrict__ Wo, const float* __restrict__ bo,
    float* __restrict__ comb)
{
  __shared__ float smem[9688];
  float* s_seq  = smem;          // [0,9216): staged seq (staging tail garbage OK)
  float* s_part = smem + 8704;   // [4][8][18] — aliases staging-overrun zone (written post-barrier)
  float* s_swn  = smem + 9280;   // [8][17]
  float* s_agg  = smem + 9416;   // [8*17]
  float* s_wp   = smem + 9552;   // [136]

  const int t = threadIdx.x;
  const int b = blockIdx.x;
  const int w = t >> 6, lane = t & 63;
  const int h = lane & 7, rg = lane >> 3;
  const float* xb = x + (size_t)b * XROW;
  const float* xs = xb + D_;

  // ---- probe: row 8*lane word0 (masked tail rows are exact zeros; live word0==0 P~1e-45)
  const float pv = xs[lane * 136];
  unsigned long long live = __ballot(pv != 0.f) | 1ull;
  const int ptop = 63 - __builtin_clzll(live);
  const int nrows = 8 * (ptop + 1);          // len <= nrows <= len+7 (rounded to 8)
  const int ng = nrows >> 2;                 // live granules (4 rows each)

  // ---- bulk stage: rounds of 256 threads x float4 (independent loads, stores after)
  {
    const int rounds = (nrows * D_ + 1023) >> 10;
    float4 tmp[9];
    #pragma unroll
    for (int j = 0; j < 9; ++j) {
      if (j < rounds) {
        int off = (j * 256 + t) * 4;
        if (off > SEQN - 4) off = SEQN - 4;  // clamp (stays inside this batch)
        tmp[j] = ld4u(xs + off);
      }
    }
    #pragma unroll
    for (int j = 0; j < 9; ++j) {
      if (j < rounds) *(float4*)&s_seq[(j * 256 + t) * 4] = tmp[j];
    }
  }

  float qk[D_];
  #pragma unroll
  for (int d = 0; d < D_; ++d) qk[d] = qkc[h*18 + d];
  const float chr = qkc[h*18 + 17];

  __syncthreads();

  float den = 0.f, acc[D_];
  #pragma unroll
  for (int d = 0; d < D_; ++d) acc[d] = 0.f;

  auto dorow = [&](const float* r, bool ok) {
    float sc = chr;
    #pragma unroll
    for (int d = 0; d < D_; ++d) sc = fmaf(qk[d], r[d], sc);
    const float p = (ok && r[0] != 0.f) ? __expf(sc) : 0.f;
    den += p;
    #pragma unroll
    for (int d = 0; d < D_; ++d) acc[d] = fmaf(p, r[d], acc[d]);
  };

  #pragma unroll 1
  for (int g0 = w * 8; g0 < ng; g0 += 32) {   // 32 granules per layer (4 waves x 8 rg)
    const int g = g0 + rg;
    const bool okg = (g < ng);
    const float* gb = &s_seq[(okg ? g : (ng - 1)) * 68];   // 16B aligned (68*g % 4 == 0)
    {
      float fA[36];
      #pragma unroll
      for (int i = 0; i < 9; ++i) {
        const float4 v = *(const float4*)(gb + 4*i);
        fA[4*i] = v.x; fA[4*i+1] = v.y; fA[4*i+2] = v.z; fA[4*i+3] = v.w;
      }
      dorow(&fA[0], okg);    // row 4g+0: words 0..16
      dorow(&fA[17], okg);   // row 4g+1: words 17..33
    }
    {
      float fB[36];
      #pragma unroll
      for (int i = 0; i < 9; ++i) {
        const float4 v = *(const float4*)(gb + 32 + 4*i);
        fB[4*i] = v.x; fB[4*i+1] = v.y; fB[4*i+2] = v.z; fB[4*i+3] = v.w;
      }
      dorow(&fB[2], okg);    // row 4g+2: words 34..50
      dorow(&fB[19], okg);   // row 4g+3: words 51..67
    }
  }

  // ---- in-wave reduce over rowgroups (8 lanes per head)
  #pragma unroll
  for (int m = 8; m <= 32; m <<= 1) {
    den += __shfl_xor(den, m, 64);
    #pragma unroll
    for (int d = 0; d < D_; ++d) acc[d] += __shfl_xor(acc[d], m, 64);
  }
  if (lane < 8) {
    float* pp = &s_part[(w * 8 + lane) * 18];
    pp[0] = den;
    #pragma unroll
    for (int d = 0; d < D_; ++d) pp[1 + d] = acc[d];
  }
  __syncthreads();

  // ---- finish
  if (t < 136) {                        // swn = (sum 4 wave-parts acc) / (sum den)
    const int hh = t / D_, d = t - hh * D_;
    float dn = 0.f, ac = 0.f;
    #pragma unroll
    for (int ww = 0; ww < 4; ++ww) {
      const float* pp = &s_part[(ww * 8 + hh) * 18];
      dn += pp[0]; ac += pp[1 + d];
    }
    s_swn[hh * D_ + d] = ac / dn;
  }
  __syncthreads();
  if (t < 136) {                        // agg = bv + Wv·swn
    const int hh = t / D_, e = t - hh * D_;
    float s = bv[hh*D_ + e];
    #pragma unroll
    for (int d = 0; d < D_; ++d) s = fmaf(Wv[hh*289 + e*D_ + d], s_swn[hh*D_ + d], s);
    s_agg[hh*D_ + e] = s;
  }
  __syncthreads();
  if (t < 136) {                        // Wo partials: 17 outs x 8 k-parts
    const int o = t >> 3, pt = t & 7;
    float s = 0.f;
    #pragma unroll
    for (int j = 0; j < D_; ++j) s = fmaf(Wo[o*136 + pt*D_ + j], s_agg[pt*D_ + j], s);
    s_wp[t] = s;
  }
  __syncthreads();
  if (t < D_) {
    float s = bo[t];
    #pragma unroll
    for (int pt = 0; pt < 8; ++pt) s += s_wp[t*8 + pt];
    comb[b*26 + t] = s;
  } else if (t < 26) {
    comb[b*26 + t] = xb[t - D_];        // special = x[b, 0, 0..8]
  }
}

// ---------------- Kernel 3: fused policy+value MLPs ----------------
// Grid 256 x 512 threads, 8 batches/block (halves W2 L2 traffic vs 4-batch).
// t = p*256 + i: thread owns output i of MLP p for all 8 batches, full k.
__global__ __launch_bounds__(512) void mlp_kernel(
    const float* __restrict__ comb,
    const float* __restrict__ pW1, const float* __restrict__ pb1,
    const float* __restrict__ pW2t, const float* __restrict__ pb2,
    const float* __restrict__ pW3, const float* __restrict__ pb3,
    const float* __restrict__ vW1, const float* __restrict__ vb1,
    const float* __restrict__ vW2t, const float* __restrict__ vb2,
    const float* __restrict__ vW3, const float* __restrict__ vb3,
    float* __restrict__ out)
{
  __shared__ float s_comb[8][26];
  __shared__ __align__(16) float s_h1[2][8][HID_];
  __shared__ __align__(16) float s_h2[2][8][HID_];

  const int t = threadIdx.x;
  const int b0 = blockIdx.x * 8;
  const int p = t >> 8;
  const int i = t & 255;

  if (t < 208) { const int bb = t / 26, k = t - bb*26; s_comb[bb][k] = comb[(size_t)(b0 + bb)*26 + k]; }
  __syncthreads();

  const float* W1  = p ? vW1  : pW1;   const float* B1 = p ? vb1 : pb1;
  const float* W2t = p ? vW2t : pW2t;  const float* B2 = p ? vb2 : pb2;

  // ---- layer 1: 26 -> 256
  {
    float a[8];
    #pragma unroll
    for (int bb = 0; bb < 8; ++bb) a[bb] = 0.f;
    const float* wr = W1 + i*26;
    for (int k = 0; k < 26; ++k) {
      const float wk = wr[k];
      #pragma unroll
      for (int bb = 0; bb < 8; ++bb) a[bb] = fmaf(wk, s_comb[bb][k], a[bb]);
    }
    const float bias = B1[i];
    #pragma unroll
    for (int bb = 0; bb < 8; ++bb) s_h1[p][bb][i] = fmaxf(a[bb] + bias, 0.f);
  }
  __syncthreads();

  // ---- layer 2: 256 -> 256 (coalesced transposed weights, broadcast LDS h)
  {
    float a[8];
    #pragma unroll
    for (int bb = 0; bb < 8; ++bb) a[bb] = 0.f;
    #pragma unroll 2
    for (int k4 = 0; k4 < 64; ++k4) {
      const int k = 4*k4;
      const float w0 = W2t[(k    )*HID_ + i];
      const float w1 = W2t[(k + 1)*HID_ + i];
      const float w2 = W2t[(k + 2)*HID_ + i];
      const float w3 = W2t[(k + 3)*HID_ + i];
      #pragma unroll
      for (int bb = 0; bb < 8; ++bb) {
        const float4 hv = *(const float4*)&s_h1[p][bb][k];   // wave-uniform broadcast
        a[bb] = fmaf(w0, hv.x, fmaf(w1, hv.y, fmaf(w2, hv.z, fmaf(w3, hv.w, a[bb]))));
      }
    }
    const float bias = B2[i];
    #pragma unroll
    for (int bb = 0; bb < 8; ++bb) s_h2[p][bb][i] = fmaxf(a[bb] + bias, 0.f);
  }
  __syncthreads();

  // ---- layer 3
  if (t < 184) {                        // policy: 8 batches x 23 outputs
    const int bb = t / OUT_, o = t - bb * OUT_;
    const float4* w4 = (const float4*)(pW3 + o * HID_);
    const float4* h4 = (const float4*)&s_h2[0][bb][0];
    float s = pb3[o];
    for (int k = 0; k < 64; ++k) {
      const float4 wv = w4[k], hv = h4[k];
      s = fmaf(wv.x, hv.x, fmaf(wv.y, hv.y, fmaf(wv.z, hv.z, fmaf(wv.w, hv.w, s))));
    }
    out[(size_t)(b0 + bb) * OUT_ + o] = s;
  } else if (t >= 256 && t < 264) {     // value: 8 batches x 1 output
    const int bb = t - 256;
    const float4* w4 = (const float4*)vW3;
    const float4* h4 = (const float4*)&s_h2[1][bb][0];
    float s = vb3[0];
    for (int k = 0; k < 64; ++k) {
      const float4 wv = w4[k], hv = h4[k];
      s = fmaf(wv.x, hv.x, fmaf(wv.y, hv.y, fmaf(wv.z, hv.z, fmaf(wv.w, hv.w, s))));
    }
    out[(size_t)B_ * OUT_ + b0 + bb] = s;
  }
}

extern "C" void kernel_launch(void* const* d_in, const int* in_sizes, int n_in,
                              void* d_out, int out_size, void* d_ws, size_t ws_size,
                              hipStream_t stream) {
  (void)in_sizes; (void)n_in; (void)out_size; (void)ws_size;
  const float* x   = (const float*)d_in[0];
  const float* Wk  = (const float*)d_in[1];
  const float* bk  = (const float*)d_in[2];
  const float* Wv  = (const float*)d_in[3];
  const float* bv  = (const float*)d_in[4];
  const float* q   = (const float*)d_in[5];
  const float* Wo  = (const float*)d_in[6];
  const float* bo  = (const float*)d_in[7];
  const float* pW1 = (const float*)d_in[8];
  const float* pb1 = (const float*)d_in[9];
  const float* pW2 = (const float*)d_in[10];
  const float* pb2 = (const float*)d_in[11];
  const float* pW3 = (const float*)d_in[12];
  const float* pb3 = (const float*)d_in[13];
  const float* vW1 = (const float*)d_in[14];
  const float* vb1 = (const float*)d_in[15];
  const float* vW2 = (const float*)d_in[16];
  const float* vb2 = (const float*)d_in[17];
  const float* vW3 = (const float*)d_in[18];
  const float* vb3 = (const float*)d_in[19];
  float* out = (float*)d_out;

  // workspace: comb (2048*26) | pW2t (65536) | vW2t (65536) | qkc (144) floats
  float* comb = (float*)d_ws;
  float* pW2t = comb + (size_t)B_ * 26;
  float* vW2t = pW2t + (size_t)HID_ * HID_;
  float* qkc  = vW2t + (size_t)HID_ * HID_;

  prep_kernel<<<129, 256, 0, stream>>>(pW2, vW2, Wk, bk, q, pW2t, vW2t, qkc);
  attn_comb_kernel<<<B_, 256, 0, stream>>>(x, qkc, Wv, bv, Wo, bo, comb);
  mlp_kernel<<<B_ / 8, 512, 0, stream>>>(comb, pW1, pb1, pW2t, pb2, pW3, pb3,
                                         vW1, vb1, vW2t, vb2, vW3, vb3, out);
}